// Round 1
// baseline (100.526 us; speedup 1.0000x reference)
//
#include <hip/hip_runtime.h>
#include <hip/hip_bf16.h>
#include <math.h>

// Problem constants
#define NROW 768
#define DIM  128

constexpr int H0c  = 256;
constexpr int H1c  = 362;
constexpr int HP1c = 368;   // H1 padded to multiple of 8 (pad cols are exact zeros)

// Workspace layout (float offsets). Total 972288 floats = ~3.9 MB.
constexpr int HX0_OFF  = 0;                         // [768][256]
constexpr int HYB0_OFF = 196608;                    // [768][256]  hy0 + b1_0
constexpr int HX1_OFF  = 393216;                    // [768][368]
constexpr int HYB1_OFF = 675840;                    // [768][368]  hy1 + b1_1
constexpr int PMAX_OFF = 958464;                    // [2][768][4] per-quarter row max
constexpr int PSUM_OFF = 964608;                    // [2][768][4] per-quarter sum(exp(t-M))
constexpr int DIAG_OFF = 970752;                    // [2][768]    t1[i,i]

// ---------------------------------------------------------------------------
// Kernel 1: hx / hy(+b1) projections.
//   m=0: hx0[i,h]  = s0[i,:] @ W1_0[0:128, h]
//   m=1: hyb0[j,h] = s1[j,:] @ W1_0[128:256, h] + b1_0[h]
//   m=2: hx1[i,h]  = [s0|s1][i,:] @ W1_1[0:256, h]
//   m=3: hyb1[j,h] = s2[j,:] @ W1_1[256:384, h] + b1_1[h]
// 8 rows per block; W1 column loads are coalesced across h=tid.
// ---------------------------------------------------------------------------
__global__ __launch_bounds__(256) void prep_kernel(
    const float* __restrict__ s0, const float* __restrict__ s1, const float* __restrict__ s2,
    const float* __restrict__ W1_0, const float* __restrict__ b1_0,
    const float* __restrict__ W1_1, const float* __restrict__ b1_1,
    float* __restrict__ ws) {
  const int m   = blockIdx.y;
  const int i0  = blockIdx.x * 8;
  const int tid = threadIdx.x;
  __shared__ float xs[8][256];

  // Stage 8 input rows (128 floats each; m==2 concatenates s0|s1 -> 256).
  const int r = tid >> 5;
  const int c = (tid & 31) * 4;
  const float* srcA = (m == 0 || m == 2) ? s0 : (m == 1 ? s1 : s2);
  *(float4*)&xs[r][c] = *(const float4*)&srcA[(i0 + r) * DIM + c];
  if (m == 2)
    *(float4*)&xs[r][DIM + c] = *(const float4*)&s1[(i0 + r) * DIM + c];
  __syncthreads();

  const int K      = (m == 2) ? 256 : 128;
  const float* W   = (m <= 1) ? W1_0 : W1_1;
  const int HREAL  = (m <= 1) ? H0c : H1c;   // also the row stride of W1
  const int HP     = (m <= 1) ? H0c : HP1c;
  const int woff   = (m == 1) ? 128 : (m == 3 ? 256 : 0);
  const float* bias = (m == 1) ? b1_0 : (m == 3 ? b1_1 : nullptr);
  float* out = ws + ((m == 0) ? HX0_OFF : (m == 1) ? HYB0_OFF : (m == 2) ? HX1_OFF : HYB1_OFF);

  for (int h = tid; h < HP; h += 256) {
    float acc[8] = {0.f, 0.f, 0.f, 0.f, 0.f, 0.f, 0.f, 0.f};
    if (h < HREAL) {
      const float* Wc = W + woff * HREAL + h;
      for (int d = 0; d < K; d += 4) {
        const float w0 = Wc[(d + 0) * HREAL];
        const float w1 = Wc[(d + 1) * HREAL];
        const float w2 = Wc[(d + 2) * HREAL];
        const float w3 = Wc[(d + 3) * HREAL];
        #pragma unroll
        for (int rr = 0; rr < 8; ++rr) {
          const float4 xv = *(const float4*)&xs[rr][d];
          acc[rr] = fmaf(xv.x, w0, acc[rr]);
          acc[rr] = fmaf(xv.y, w1, acc[rr]);
          acc[rr] = fmaf(xv.z, w2, acc[rr]);
          acc[rr] = fmaf(xv.w, w3, acc[rr]);
        }
      }
      const float bv = bias ? bias[h] : 0.f;
      #pragma unroll
      for (int rr = 0; rr < 8; ++rr) acc[rr] += bv;
    }
    #pragma unroll
    for (int rr = 0; rr < 8; ++rr) out[(i0 + rr) * HP + h] = acc[rr];  // pad cols -> 0
  }
}

// ---------------------------------------------------------------------------
// Kernel 2: all-pairs t1 tile + per-row partial logsumexp.
// Block = 8 j-rows x 192 i-columns. Each thread: 1 i, 8 j accumulators.
// ---------------------------------------------------------------------------
template <int HP, int HREAL>
__device__ __forceinline__ void pair_body(
    const float* __restrict__ hx, const float* __restrict__ hyb,
    const float* __restrict__ W2,
    float* __restrict__ pmax, float* __restrict__ psum, float* __restrict__ diag,
    float* sh) {
  float* ys    = sh;                 // [8][HP]
  float* w2s   = sh + 8 * HP;        // [HP]
  float* wredm = w2s + HP;           // [3][8]
  float* wreds = wredm + 24;         // [3][8]

  const int tid = threadIdx.x;
  const int j0  = blockIdx.x * 8;
  const int iq  = blockIdx.y;
  const int i   = iq * 192 + tid;

  #pragma unroll
  for (int r = 0; r < 8; ++r)
    for (int h = tid; h < HP; h += 192)
      ys[r * HP + h] = hyb[(j0 + r) * HP + h];
  for (int h = tid; h < HP; h += 192)
    w2s[h] = (h < HREAL) ? W2[h] : 0.f;
  __syncthreads();

  float acc[8] = {0.f, 0.f, 0.f, 0.f, 0.f, 0.f, 0.f, 0.f};
  const float* hxr = hx + i * HP;
  for (int hb = 0; hb < HP; hb += 4) {
    const float4 a = *(const float4*)(hxr + hb);
    const float4 w = *(const float4*)(w2s + hb);
    #pragma unroll
    for (int r = 0; r < 8; ++r) {
      const float4 y = *(const float4*)(ys + r * HP + hb);
      acc[r] = fmaf(fmaxf(a.x + y.x, 0.f), w.x, acc[r]);
      acc[r] = fmaf(fmaxf(a.y + y.y, 0.f), w.y, acc[r]);
      acc[r] = fmaf(fmaxf(a.z + y.z, 0.f), w.z, acc[r]);
      acc[r] = fmaf(fmaxf(a.w + y.w, 0.f), w.w, acc[r]);
    }
  }

  // diagonal t1[i,i] (== t0[i]; b2 cancels against lse so it is omitted)
  #pragma unroll
  for (int r = 0; r < 8; ++r)
    if (i == j0 + r) diag[i] = acc[r];

  const int lane = tid & 63;
  const int wv   = tid >> 6;  // 0..2

  float M[8];
  #pragma unroll
  for (int r = 0; r < 8; ++r) {
    float mm = acc[r];
    #pragma unroll
    for (int off = 32; off > 0; off >>= 1) mm = fmaxf(mm, __shfl_xor(mm, off));
    M[r] = mm;
  }
  if (lane == 0) {
    #pragma unroll
    for (int r = 0; r < 8; ++r) wredm[wv * 8 + r] = M[r];
  }
  __syncthreads();
  #pragma unroll
  for (int r = 0; r < 8; ++r)
    M[r] = fmaxf(fmaxf(wredm[r], wredm[8 + r]), wredm[16 + r]);

  #pragma unroll
  for (int r = 0; r < 8; ++r) {
    float e = expf(acc[r] - M[r]);
    #pragma unroll
    for (int off = 32; off > 0; off >>= 1) e += __shfl_xor(e, off);
    if (lane == 0) wreds[wv * 8 + r] = e;
  }
  __syncthreads();
  if (tid < 8) {
    const int row = j0 + tid;
    pmax[row * 4 + iq] = M[tid];
    psum[row * 4 + iq] = wreds[tid] + wreds[8 + tid] + wreds[16 + tid];
  }
}

__global__ __launch_bounds__(192) void pair_kernel(
    float* __restrict__ ws, const float* __restrict__ W2_0, const float* __restrict__ W2_1) {
  __shared__ float sh[8 * HP1c + HP1c + 48];
  if (blockIdx.z == 0)
    pair_body<H0c, H0c>(ws + HX0_OFF, ws + HYB0_OFF, W2_0,
                        ws + PMAX_OFF, ws + PSUM_OFF, ws + DIAG_OFF, sh);
  else
    pair_body<HP1c, H1c>(ws + HX1_OFF, ws + HYB1_OFF, W2_1,
                         ws + PMAX_OFF + 3072, ws + PSUM_OFF + 3072, ws + DIAG_OFF + NROW, sh);
}

// ---------------------------------------------------------------------------
// Kernel 3: merge quarter partials -> per-row lse; sum (diag - lse); scalar out.
// ---------------------------------------------------------------------------
__global__ __launch_bounds__(1024) void final_kernel(
    const float* __restrict__ ws, float* __restrict__ out) {
  __shared__ float red[1024];
  const int t = threadIdx.x;
  float val = 0.f;
  if (t < NROW) {
    #pragma unroll
    for (int est = 0; est < 2; ++est) {
      const float* pm = ws + PMAX_OFF + est * 3072 + t * 4;
      const float* ps = ws + PSUM_OFF + est * 3072 + t * 4;
      float M = fmaxf(fmaxf(pm[0], pm[1]), fmaxf(pm[2], pm[3]));
      float S = ps[0] * expf(pm[0] - M) + ps[1] * expf(pm[1] - M) +
                ps[2] * expf(pm[2] - M) + ps[3] * expf(pm[3] - M);
      float lse = M + logf(S);
      float dg  = ws[DIAG_OFF + est * NROW + t];
      val += dg - lse;
    }
  }
  red[t] = val;
  __syncthreads();
  for (int s = 512; s > 0; s >>= 1) {
    if (t < s) red[t] += red[t + s];
    __syncthreads();
  }
  if (t == 0) out[0] = red[0] * (1.0f / (float)NROW) + 2.0f * logf((float)NROW);
}

// ---------------------------------------------------------------------------
extern "C" void kernel_launch(void* const* d_in, const int* in_sizes, int n_in,
                              void* d_out, int out_size, void* d_ws, size_t ws_size,
                              hipStream_t stream) {
  const float* s0   = (const float*)d_in[0];
  const float* s1   = (const float*)d_in[1];
  const float* s2   = (const float*)d_in[2];
  const float* W1_0 = (const float*)d_in[3];
  const float* b1_0 = (const float*)d_in[4];
  const float* W2_0 = (const float*)d_in[5];
  // d_in[6] = b2_0 (cancels exactly; unused)
  const float* W1_1 = (const float*)d_in[7];
  const float* b1_1 = (const float*)d_in[8];
  const float* W2_1 = (const float*)d_in[9];
  // d_in[10] = b2_1 (cancels exactly; unused)
  float* ws  = (float*)d_ws;   // needs ~3.9 MB
  float* out = (float*)d_out;

  hipLaunchKernelGGL(prep_kernel, dim3(96, 4), dim3(256), 0, stream,
                     s0, s1, s2, W1_0, b1_0, W1_1, b1_1, ws);
  hipLaunchKernelGGL(pair_kernel, dim3(96, 4, 2), dim3(192), 0, stream,
                     ws, W2_0, W2_1);
  hipLaunchKernelGGL(final_kernel, dim3(1), dim3(1024), 0, stream, ws, out);
}

// Round 2
// 58.636 us; speedup vs baseline: 1.7144x; 1.7144x over previous
//
#include <hip/hip_runtime.h>
#include <hip/hip_bf16.h>
#include <math.h>

#define NROW 768
#define DIM  128

constexpr int H0c  = 256;
constexpr int H1c  = 362;
constexpr int HP1c = 368;   // H1 padded; pad columns are exact zeros

// Workspace layout (float offsets). ~3.9 MB total.
// hx stored in PANEL layout: [HP/4 panels][768 rows][4 h] so that the pair
// kernel's per-thread read hx[i, hb..hb+3] is one coalesced float4 (lane = i).
constexpr int HX0_OFF  = 0;         // [64][768][4]
constexpr int HYB0_OFF = 196608;    // [768][256]   hy0 + b1_0 (row-major)
constexpr int HX1_OFF  = 393216;    // [92][768][4]
constexpr int HYB1_OFF = 675840;    // [768][368]   hy1 + b1_1 (row-major)
constexpr int PMAX_OFF = 958464;    // [2][768][4]  (slots 0..2 used)
constexpr int PSUM_OFF = 964608;    // [2][768][4]
constexpr int DIAG_OFF = 970752;    // [2][768]

// ---------------------------------------------------------------------------
// prep: the four projections.
//   by -> (m, htile):  0:(0,0) 1:(1,0) 2:(2,0) 3:(2,1) 4:(3,0) 5:(3,1)
//   m=0: hx0  = s0 @ W1_0[0:128]            -> panel layout
//   m=1: hyb0 = s1 @ W1_0[128:256] + b1_0   -> row-major
//   m=2: hx1  = [s0|s1] @ W1_1[0:256]       -> panel layout
//   m=3: hyb1 = s2 @ W1_1[256:384] + b1_1   -> row-major
// block = (64 h-threads x 4 row-groups); thread: 4 h x 4 rows = 16 accums.
// W loads are coalesced float4 along h; x comes from LDS (broadcast).
// ---------------------------------------------------------------------------
__global__ __launch_bounds__(256) void prep_kernel(
    const float* __restrict__ s0, const float* __restrict__ s1, const float* __restrict__ s2,
    const float* __restrict__ W1_0, const float* __restrict__ b1_0,
    const float* __restrict__ W1_1, const float* __restrict__ b1_1,
    float* __restrict__ ws) {
  const int by = blockIdx.y;
  const int m  = (by < 2) ? by : (by < 4) ? 2 : 3;
  const int ht = (by == 3 || by == 5) ? 1 : 0;

  const int i0  = blockIdx.x * 16;
  const int tx  = threadIdx.x;           // 0..63
  const int ty  = threadIdx.y;           // 0..3
  const int tid = ty * 64 + tx;

  const int K      = (m == 2) ? 256 : 128;
  const int HREAL  = (m <= 1) ? H0c : H1c;
  const int HP     = (m <= 1) ? H0c : HP1c;
  const float* W   = (m <= 1) ? W1_0 : W1_1;
  const int woff   = (m == 1) ? 128 : (m == 3) ? 256 : 0;
  const float* bias = (m == 1) ? b1_0 : (m == 3) ? b1_1 : nullptr;

  __shared__ float xs[16][256];

  // stage 16 input rows (m==2: concat s0|s1)
  {
    const int nf4 = 16 * (K / 4);
    const float* sa = (m == 3) ? s2 : (m == 1) ? s1 : s0;
    for (int idx = tid; idx < nf4; idx += 256) {
      const int row = idx / (K / 4);
      const int c4  = (idx % (K / 4)) * 4;
      float4 v;
      if (m == 2 && c4 >= 128)
        v = *(const float4*)&s1[(i0 + row) * DIM + (c4 - 128)];
      else
        v = *(const float4*)&sa[(i0 + row) * DIM + c4];
      *(float4*)&xs[row][c4] = v;
    }
  }
  __syncthreads();

  const int h4 = ht * 256 + tx * 4;
  if (h4 >= HP) return;    // no barriers after this point

  const int r0 = ty * 4;
  float acc[4][4] = {};

  for (int d = 0; d < K; d += 4) {
    float4 xv[4];
    #pragma unroll
    for (int r = 0; r < 4; ++r) xv[r] = *(const float4*)&xs[r0 + r][d];
    float4 wv[4];
    #pragma unroll
    for (int dd = 0; dd < 4; ++dd)
      wv[dd] = *(const float4*)&W[(woff + d + dd) * HREAL + h4];
    #pragma unroll
    for (int dd = 0; dd < 4; ++dd) {
      #pragma unroll
      for (int r = 0; r < 4; ++r) {
        const float xval = ((const float*)&xv[r])[dd];
        acc[r][0] = fmaf(xval, wv[dd].x, acc[r][0]);
        acc[r][1] = fmaf(xval, wv[dd].y, acc[r][1]);
        acc[r][2] = fmaf(xval, wv[dd].z, acc[r][2]);
        acc[r][3] = fmaf(xval, wv[dd].w, acc[r][3]);
      }
    }
  }

  // bias (masked; pad columns h>=HREAL stay exact zero)
  float bv[4] = {0.f, 0.f, 0.f, 0.f};
  if (bias) {
    #pragma unroll
    for (int hk = 0; hk < 4; ++hk)
      if (h4 + hk < HREAL) bv[hk] = bias[h4 + hk];
  }
  const bool ok0 = (h4 + 0 < HREAL), ok1 = (h4 + 1 < HREAL),
             ok2 = (h4 + 2 < HREAL), ok3 = (h4 + 3 < HREAL);

  float* outp = ws + ((m == 0) ? HX0_OFF : (m == 1) ? HYB0_OFF
                    : (m == 2) ? HX1_OFF : HYB1_OFF);
  if ((m & 1) == 0) {
    const int pbase = (h4 >> 2) * (NROW * 4);
    #pragma unroll
    for (int r = 0; r < 4; ++r) {
      float4 v;
      v.x = ok0 ? acc[r][0] : 0.f;
      v.y = ok1 ? acc[r][1] : 0.f;
      v.z = ok2 ? acc[r][2] : 0.f;
      v.w = ok3 ? acc[r][3] : 0.f;
      *(float4*)&outp[pbase + (i0 + r0 + r) * 4] = v;
    }
  } else {
    #pragma unroll
    for (int r = 0; r < 4; ++r) {
      float4 v;
      v.x = ok0 ? acc[r][0] + bv[0] : 0.f;
      v.y = ok1 ? acc[r][1] + bv[1] : 0.f;
      v.z = ok2 ? acc[r][2] + bv[2] : 0.f;
      v.w = ok3 ? acc[r][3] + bv[3] : 0.f;
      *(float4*)&outp[(i0 + r0 + r) * HP + h4] = v;
    }
  }
}

// ---------------------------------------------------------------------------
// pair: t1 tile + per-row partial logsumexp.
// Block = 4 j-rows x 256 i-columns; thread: 1 i, 4 j accumulators.
// hx via coalesced panel float4; ys/W2 broadcast from LDS.
// Grid: (192 j-tiles, 3 i-quarters, 2 estimators) = 1152 blocks (4.5 w/SIMD).
// ---------------------------------------------------------------------------
template <int HP, int HREAL>
__device__ __forceinline__ void pair_body(
    const float* __restrict__ hx4, const float* __restrict__ hyb,
    const float* __restrict__ W2,
    float* __restrict__ pmax, float* __restrict__ psum, float* __restrict__ diag,
    float* sh) {
  float* ys   = sh;             // [4][HP]
  float* w2s  = sh + 4 * HP;    // [HP]
  float* redm = w2s + HP;       // [4 waves][4 rows]
  float* reds = redm + 16;      // [4 waves][4 rows]

  const int tid = threadIdx.x;          // 0..255
  const int j0  = blockIdx.x * 4;
  const int iq  = blockIdx.y;           // 0..2
  const int i   = iq * 256 + tid;

  {
    const int r = tid >> 6;
    for (int h4 = (tid & 63) * 4; h4 < HP; h4 += 256)
      *(float4*)&ys[r * HP + h4] = *(const float4*)&hyb[(j0 + r) * HP + h4];
  }
  for (int h = tid; h < HP; h += 256)
    w2s[h] = (h < HREAL) ? W2[h] : 0.f;
  __syncthreads();

  float acc[4] = {0.f, 0.f, 0.f, 0.f};
  const float* xp = hx4 + i * 4;
  #pragma unroll 2
  for (int hb = 0; hb < HP; hb += 4, xp += NROW * 4) {
    const float4 a  = *(const float4*)xp;
    const float4 w  = *(const float4*)&w2s[hb];
    const float4 y0 = *(const float4*)&ys[hb];
    const float4 y1 = *(const float4*)&ys[HP + hb];
    const float4 y2 = *(const float4*)&ys[2 * HP + hb];
    const float4 y3 = *(const float4*)&ys[3 * HP + hb];
    acc[0] = fmaf(fmaxf(a.x + y0.x, 0.f), w.x, acc[0]);
    acc[0] = fmaf(fmaxf(a.y + y0.y, 0.f), w.y, acc[0]);
    acc[0] = fmaf(fmaxf(a.z + y0.z, 0.f), w.z, acc[0]);
    acc[0] = fmaf(fmaxf(a.w + y0.w, 0.f), w.w, acc[0]);
    acc[1] = fmaf(fmaxf(a.x + y1.x, 0.f), w.x, acc[1]);
    acc[1] = fmaf(fmaxf(a.y + y1.y, 0.f), w.y, acc[1]);
    acc[1] = fmaf(fmaxf(a.z + y1.z, 0.f), w.z, acc[1]);
    acc[1] = fmaf(fmaxf(a.w + y1.w, 0.f), w.w, acc[1]);
    acc[2] = fmaf(fmaxf(a.x + y2.x, 0.f), w.x, acc[2]);
    acc[2] = fmaf(fmaxf(a.y + y2.y, 0.f), w.y, acc[2]);
    acc[2] = fmaf(fmaxf(a.z + y2.z, 0.f), w.z, acc[2]);
    acc[2] = fmaf(fmaxf(a.w + y2.w, 0.f), w.w, acc[2]);
    acc[3] = fmaf(fmaxf(a.x + y3.x, 0.f), w.x, acc[3]);
    acc[3] = fmaf(fmaxf(a.y + y3.y, 0.f), w.y, acc[3]);
    acc[3] = fmaf(fmaxf(a.z + y3.z, 0.f), w.z, acc[3]);
    acc[3] = fmaf(fmaxf(a.w + y3.w, 0.f), w.w, acc[3]);
  }

  // diagonal t1[i,i] (b2 cancels against lse; omitted everywhere)
  const int dj = i - j0;
  if (dj == 0) diag[i] = acc[0];
  else if (dj == 1) diag[i] = acc[1];
  else if (dj == 2) diag[i] = acc[2];
  else if (dj == 3) diag[i] = acc[3];

  const int lane = tid & 63;
  const int wv   = tid >> 6;

  float M[4];
  #pragma unroll
  for (int r = 0; r < 4; ++r) {
    float mm = acc[r];
    #pragma unroll
    for (int off = 32; off > 0; off >>= 1) mm = fmaxf(mm, __shfl_xor(mm, off));
    M[r] = mm;
  }
  if (lane == 0) {
    #pragma unroll
    for (int r = 0; r < 4; ++r) redm[wv * 4 + r] = M[r];
  }
  __syncthreads();
  #pragma unroll
  for (int r = 0; r < 4; ++r)
    M[r] = fmaxf(fmaxf(redm[r], redm[4 + r]), fmaxf(redm[8 + r], redm[12 + r]));

  #pragma unroll
  for (int r = 0; r < 4; ++r) {
    float e = __expf(acc[r] - M[r]);
    #pragma unroll
    for (int off = 32; off > 0; off >>= 1) e += __shfl_xor(e, off);
    if (lane == 0) reds[wv * 4 + r] = e;
  }
  __syncthreads();
  if (tid < 4) {
    const float m = fmaxf(fmaxf(redm[tid], redm[4 + tid]),
                          fmaxf(redm[8 + tid], redm[12 + tid]));
    const float s = reds[tid] + reds[4 + tid] + reds[8 + tid] + reds[12 + tid];
    pmax[(j0 + tid) * 4 + iq] = m;
    psum[(j0 + tid) * 4 + iq] = s;
  }
}

__global__ __launch_bounds__(256) void pair_kernel(
    float* __restrict__ ws, const float* __restrict__ W2_0, const float* __restrict__ W2_1) {
  __shared__ float sh[4 * HP1c + HP1c + 32];
  if (blockIdx.z == 0)
    pair_body<H0c, H0c>(ws + HX0_OFF, ws + HYB0_OFF, W2_0,
                        ws + PMAX_OFF, ws + PSUM_OFF, ws + DIAG_OFF, sh);
  else
    pair_body<HP1c, H1c>(ws + HX1_OFF, ws + HYB1_OFF, W2_1,
                         ws + PMAX_OFF + 3072, ws + PSUM_OFF + 3072, ws + DIAG_OFF + NROW, sh);
}

// ---------------------------------------------------------------------------
// final: merge 3 i-quarter partials -> per-row lse; sum (diag - lse); scalar.
// ---------------------------------------------------------------------------
__global__ __launch_bounds__(1024) void final_kernel(
    const float* __restrict__ ws, float* __restrict__ out) {
  __shared__ float red[1024];
  const int t = threadIdx.x;
  float val = 0.f;
  if (t < NROW) {
    #pragma unroll
    for (int est = 0; est < 2; ++est) {
      const float* pm = ws + PMAX_OFF + est * 3072 + t * 4;
      const float* ps = ws + PSUM_OFF + est * 3072 + t * 4;
      float M = fmaxf(fmaxf(pm[0], pm[1]), pm[2]);
      float S = ps[0] * __expf(pm[0] - M) + ps[1] * __expf(pm[1] - M) +
                ps[2] * __expf(pm[2] - M);
      float lse = M + logf(S);
      val += ws[DIAG_OFF + est * NROW + t] - lse;
    }
  }
  red[t] = val;
  __syncthreads();
  for (int s = 512; s > 0; s >>= 1) {
    if (t < s) red[t] += red[t + s];
    __syncthreads();
  }
  if (t == 0) out[0] = red[0] * (1.0f / (float)NROW) + 2.0f * logf((float)NROW);
}

// ---------------------------------------------------------------------------
extern "C" void kernel_launch(void* const* d_in, const int* in_sizes, int n_in,
                              void* d_out, int out_size, void* d_ws, size_t ws_size,
                              hipStream_t stream) {
  const float* s0   = (const float*)d_in[0];
  const float* s1   = (const float*)d_in[1];
  const float* s2   = (const float*)d_in[2];
  const float* W1_0 = (const float*)d_in[3];
  const float* b1_0 = (const float*)d_in[4];
  const float* W2_0 = (const float*)d_in[5];
  const float* W1_1 = (const float*)d_in[7];
  const float* b1_1 = (const float*)d_in[8];
  const float* W2_1 = (const float*)d_in[9];
  float* ws  = (float*)d_ws;
  float* out = (float*)d_out;

  hipLaunchKernelGGL(prep_kernel, dim3(48, 6), dim3(64, 4), 0, stream,
                     s0, s1, s2, W1_0, b1_0, W1_1, b1_1, ws);
  hipLaunchKernelGGL(pair_kernel, dim3(192, 3, 2), dim3(256), 0, stream,
                     ws, W2_0, W2_1);
  hipLaunchKernelGGL(final_kernel, dim3(1), dim3(1024), 0, stream, ws, out);
}